// Round 4
// baseline (68.618 us; speedup 1.0000x reference)
//
#include <hip/hip_runtime.h>

// Problem geometry (fixed by the reference): u is (B=2, C=3, D=160, H=192, W=160) float32.
#define Dd 160
#define Hh 192
#define Ww 160
#define HW (Hh * Ww)                       // 30720
#define DHW ((size_t)Dd * HW)              // 4,915,200
#define NVOX_D 9830400.0                   // 2 * 160*192*160
#define QROW (Ww / 4)                      // 40 float4-quads per row
#define QUADS 2457600                      // NVOX / 4
#define BLK 256
#define GRID1 (QUADS / BLK)                // 9600 blocks, exact

__device__ __forceinline__ float4 ld4(const float* p) {
    return *reinterpret_cast<const float4*>(p);
}

// relu(-det(J)) for one voxel given the 9 raw (unscaled) finite-difference
// gradients of u. phi = u * scale per channel, so grad(phi_c) = s_c * grad(u_c).
__device__ __forceinline__ float relu_negdet(
    float gd0, float gh0, float gw0,
    float gd1, float gh1, float gw1,
    float gd2, float gh2, float gw2)
{
    const float sx = 79.5f;   // (D-1)/2 -> channel 0
    const float sy = 95.5f;   // (H-1)/2 -> channel 1
    const float sz = 79.5f;   // (W-1)/2 -> channel 2
    float dxx = fmaf(sx, gd0, 1.0f);
    float dxy = sx * gh0;
    float dxz = sx * gw0;
    float dyx = sy * gd1;
    float dyy = fmaf(sy, gh1, 1.0f);
    float dyz = sy * gw1;
    float dzx = sz * gd2;
    float dzy = sz * gh2;
    float dzz = fmaf(sz, gw2, 1.0f);
    float det = dxx * (dyy * dzz - dyz * dzy)
              + dxy * (dyz * dzx - dyx * dzz)
              + dxz * (dyx * dzy - dyy * dzx);
    return fmaxf(-det, 0.0f);
}

__global__ __launch_bounds__(BLK) void jac_partial(const float* __restrict__ u,
                                                   float* __restrict__ part)
{
    int q  = blockIdx.x * BLK + threadIdx.x;   // quad id, < QUADS
    int wq = q % QROW;  int t = q / QROW;
    int h  = t % Hh;    t /= Hh;
    int d  = t % Dd;    int b = t / Dd;
    int w0 = wq * 4;

    // jnp.gradient edge handling via clamped indices:
    // interior: (a[i+1]-a[i-1])/2 ; edge: (a[1]-a[0])/1  -- both are (a[ip]-a[im])/(ip-im)
    int hm = (h > 0)      ? h - 1 : 0;
    int hp = (h < Hh - 1) ? h + 1 : Hh - 1;
    float hinv = 1.0f / (float)(hp - hm);
    int dm = (d > 0)      ? d - 1 : 0;
    int dp = (d < Dd - 1) ? d + 1 : Dd - 1;
    float dinv = 1.0f / (float)(dp - dm);
    int drm = (hm - h) * Ww;    // 0 or -Ww
    int drp = (hp - h) * Ww;    // 0 or +Ww
    int dpm = (dm - d) * HW;    // 0 or -HW
    int dpp = (dp - d) * HW;    // 0 or +HW

    size_t vox = (size_t)d * HW + (size_t)h * Ww + (size_t)w0;

    float4 gd[3], gh[3], gw[3];
    #pragma unroll
    for (int c = 0; c < 3; ++c) {
        const float* p = u + ((size_t)(b * 3 + c)) * DHW + vox;
        float4 cc = ld4(p);

        // w-gradient: neighbors live in cc except the two quad-boundary scalars
        float lft = (w0 > 0)      ? p[-1] : 0.0f;   // guarded: no OOB at buffer start
        float rgt = (w0 + 4 < Ww) ? p[4]  : 0.0f;
        float4 g;
        g.x = (w0 == 0)      ? (cc.y - cc.x) : 0.5f * (cc.y - lft);
        g.y = 0.5f * (cc.z - cc.x);
        g.z = 0.5f * (cc.w - cc.y);
        g.w = (w0 + 4 == Ww) ? (cc.w - cc.z) : 0.5f * (rgt - cc.z);
        gw[c] = g;

        // h-gradient
        float4 rm = ld4(p + drm), rp = ld4(p + drp);
        gh[c] = make_float4((rp.x - rm.x) * hinv, (rp.y - rm.y) * hinv,
                            (rp.z - rm.z) * hinv, (rp.w - rm.w) * hinv);

        // d-gradient
        float4 pm = ld4(p + dpm), pp = ld4(p + dpp);
        gd[c] = make_float4((pp.x - pm.x) * dinv, (pp.y - pm.y) * dinv,
                            (pp.z - pm.z) * dinv, (pp.w - pm.w) * dinv);
    }

    float acc =
        relu_negdet(gd[0].x, gh[0].x, gw[0].x, gd[1].x, gh[1].x, gw[1].x, gd[2].x, gh[2].x, gw[2].x)
      + relu_negdet(gd[0].y, gh[0].y, gw[0].y, gd[1].y, gh[1].y, gw[1].y, gd[2].y, gh[2].y, gw[2].y)
      + relu_negdet(gd[0].z, gh[0].z, gw[0].z, gd[1].z, gh[1].z, gw[1].z, gd[2].z, gh[2].z, gw[2].z)
      + relu_negdet(gd[0].w, gh[0].w, gw[0].w, gd[1].w, gh[1].w, gw[1].w, gd[2].w, gh[2].w, gw[2].w);

    // deterministic block reduction: wave64 shuffle tree, then 4-word LDS
    #pragma unroll
    for (int off = 32; off > 0; off >>= 1)
        acc += __shfl_down(acc, off, 64);
    __shared__ float sred[BLK / 64];
    int lane = threadIdx.x & 63;
    int wid  = threadIdx.x >> 6;
    if (lane == 0) sred[wid] = acc;
    __syncthreads();
    if (threadIdx.x == 0)
        part[blockIdx.x] = (sred[0] + sred[1]) + (sred[2] + sred[3]);
}

// Single-block deterministic final reduce in f64 (sum ~2e8; f32 alone would
// cost ~1e-5 relative, f64 makes it exact vs the 2% tolerance).
__global__ __launch_bounds__(BLK) void jac_final(const float* __restrict__ part,
                                                 float* __restrict__ out, int n)
{
    __shared__ double s[BLK];
    double acc = 0.0;
    for (int i = threadIdx.x; i < n; i += BLK) acc += (double)part[i];
    s[threadIdx.x] = acc;
    __syncthreads();
    #pragma unroll
    for (int off = BLK / 2; off > 0; off >>= 1) {
        if (threadIdx.x < off) s[threadIdx.x] += s[threadIdx.x + off];
        __syncthreads();
    }
    if (threadIdx.x == 0)
        out[0] = (float)(s[0] / NVOX_D);
}

extern "C" void kernel_launch(void* const* d_in, const int* in_sizes, int n_in,
                              void* d_out, int out_size, void* d_ws, size_t ws_size,
                              hipStream_t stream)
{
    const float* u = (const float*)d_in[0];
    float* part = (float*)d_ws;              // 9600 floats = 38.4 KB of scratch

    jac_partial<<<GRID1, BLK, 0, stream>>>(u, part);
    jac_final<<<1, BLK, 0, stream>>>(part, (float*)d_out, GRID1);
}

// Round 5
// 38.643 us; speedup vs baseline: 1.7757x; 1.7757x over previous
//
#include <hip/hip_runtime.h>

// Problem geometry (fixed by the reference): u is (B=2, C=3, D=160, H=192, W=160) float32.
#define Dd 160
#define Hh 192
#define Ww 160
#define HW (Hh * Ww)                       // 30720
#define DHW ((size_t)Dd * HW)              // 4,915,200
#define NVOX_D 9830400.0                   // 2 * 160*192*160

#define TH 8                                // h-rows per block
#define TD 10                               // d-planes per block (sliding window)
#define QROW (Ww / 4)                       // 40 float4-quads per row
#define TPB (QROW * TH)                     // 320 threads = 5 waves
#define NHT (Hh / TH)                       // 24
#define NDS (Dd / TD)                       // 16
#define GRID1 (2 * NHT * NDS)               // 768 blocks = exactly 3 per CU
#define BLK2 256

__device__ __forceinline__ float4 ld4(const float* p) {
    return *reinterpret_cast<const float4*>(p);
}

// w-gradient for a quad given its left/right edge scalars (jnp.gradient semantics)
__device__ __forceinline__ float4 wgrad(float4 cc, float lft, float rgt, int w0) {
    float4 g;
    g.x = (w0 == 0)      ? (cc.y - cc.x) : 0.5f * (cc.y - lft);
    g.y = 0.5f * (cc.z - cc.x);
    g.z = 0.5f * (cc.w - cc.y);
    g.w = (w0 + 4 == Ww) ? (cc.w - cc.z) : 0.5f * (rgt - cc.z);
    return g;
}

// relu(-det(J)) for one voxel given the 9 raw (unscaled) finite-difference grads.
__device__ __forceinline__ float relu_negdet(
    float gd0, float gh0, float gw0,
    float gd1, float gh1, float gw1,
    float gd2, float gh2, float gw2)
{
    const float sx = 79.5f;   // (D-1)/2 -> channel 0
    const float sy = 95.5f;   // (H-1)/2 -> channel 1
    const float sz = 79.5f;   // (W-1)/2 -> channel 2
    float dxx = fmaf(sx, gd0, 1.0f);
    float dxy = sx * gh0;
    float dxz = sx * gw0;
    float dyx = sy * gd1;
    float dyy = fmaf(sy, gh1, 1.0f);
    float dyz = sy * gw1;
    float dzx = sz * gd2;
    float dzy = sz * gh2;
    float dzz = fmaf(sz, gw2, 1.0f);
    float det = dxx * (dyy * dzz - dyz * dzy)
              + dxy * (dyz * dzx - dyx * dzz)
              + dxz * (dyx * dzy - dyy * dzx);
    return fmaxf(-det, 0.0f);
}

// Register-sliding d-march: each thread owns one w-quad in one h-row and walks
// TD planes, keeping center quads at d-1/d/d+1 for all 3 channels in registers.
// Per step it loads only the new d+1 plane quad + the two h-neighbor quads
// (L1/L2 hits: siblings loaded them as centers one step earlier) + 2 edge scalars.
__global__ __launch_bounds__(TPB) void jac_partial(const float* __restrict__ u,
                                                   float* __restrict__ part)
{
    const int gid = blockIdx.x;
    const int ds  = gid % NDS;
    const int ht  = (gid / NDS) % NHT;
    const int b   = gid / (NDS * NHT);

    const int tid = threadIdx.x;
    const int wq  = tid % QROW;
    const int hh  = tid / QROW;
    const int h   = ht * TH + hh;
    const int w0  = wq * 4;

    // jnp.gradient edge handling via clamped indices (one-sided at h=0/H-1)
    const int hm = (h > 0)      ? h - 1 : 0;
    const int hp = (h < Hh - 1) ? h + 1 : Hh - 1;
    const float hinv = 1.0f / (float)(hp - hm);
    const int offm = (hm - h) * Ww;   // 0 or -Ww
    const int offp = (hp - h) * Ww;   // 0 or +Ww

    const int d0 = ds * TD;

    // channel base pointers at (b, c, d=0, h, w0)
    const float* pcA = u + (size_t)(b * 3 + 0) * DHW + (size_t)h * Ww + w0;
    const float* pcB = pcA + DHW;
    const float* pcC = pcA + 2 * DHW;

    // sliding window: channel {A,B,C} center quads at planes d-1 (x0), d (x1)
    float4 a0, a1, b0, b1, c0, c1;
    {
        const size_t om = (size_t)((d0 > 0) ? d0 - 1 : 0) * HW;
        const size_t oc = (size_t)d0 * HW;
        a0 = ld4(pcA + om);  a1 = ld4(pcA + oc);
        b0 = ld4(pcB + om);  b1 = ld4(pcB + oc);
        c0 = ld4(pcC + om);  c1 = ld4(pcC + oc);
    }

    float acc = 0.0f;

    #pragma unroll 2
    for (int d = d0; d < d0 + TD; ++d) {
        const int dp = (d < Dd - 1) ? d + 1 : Dd - 1;
        const float dinv = (d > 0 && d < Dd - 1) ? 0.5f : 1.0f;
        const size_t od  = (size_t)d  * HW;
        const size_t odp = (size_t)dp * HW;

        // issue next-plane center loads first (consumed last -> latency hidden)
        float4 a2 = ld4(pcA + odp);
        float4 b2 = ld4(pcB + odp);
        float4 c2 = ld4(pcC + odp);

        const float* pdA = pcA + od;
        const float* pdB = pcB + od;
        const float* pdC = pcC + od;

        // h-neighbor quads at plane d (cache hits)
        float4 rAm = ld4(pdA + offm), rAp = ld4(pdA + offp);
        float4 rBm = ld4(pdB + offm), rBp = ld4(pdB + offp);
        float4 rCm = ld4(pdC + offm), rCp = ld4(pdC + offp);

        // w-edge scalars (cache hits)
        float lA = (w0 > 0) ? pdA[-1] : 0.0f;
        float lB = (w0 > 0) ? pdB[-1] : 0.0f;
        float lC = (w0 > 0) ? pdC[-1] : 0.0f;
        float rA = (w0 + 4 < Ww) ? pdA[4] : 0.0f;
        float rB = (w0 + 4 < Ww) ? pdB[4] : 0.0f;
        float rC = (w0 + 4 < Ww) ? pdC[4] : 0.0f;

        // gradients (raw, unscaled)
        float4 gwA = wgrad(a1, lA, rA, w0);
        float4 gwB = wgrad(b1, lB, rB, w0);
        float4 gwC = wgrad(c1, lC, rC, w0);

        float4 ghA = make_float4((rAp.x - rAm.x) * hinv, (rAp.y - rAm.y) * hinv,
                                 (rAp.z - rAm.z) * hinv, (rAp.w - rAm.w) * hinv);
        float4 ghB = make_float4((rBp.x - rBm.x) * hinv, (rBp.y - rBm.y) * hinv,
                                 (rBp.z - rBm.z) * hinv, (rBp.w - rBm.w) * hinv);
        float4 ghC = make_float4((rCp.x - rCm.x) * hinv, (rCp.y - rCm.y) * hinv,
                                 (rCp.z - rCm.z) * hinv, (rCp.w - rCm.w) * hinv);

        float4 gdA = make_float4((a2.x - a0.x) * dinv, (a2.y - a0.y) * dinv,
                                 (a2.z - a0.z) * dinv, (a2.w - a0.w) * dinv);
        float4 gdB = make_float4((b2.x - b0.x) * dinv, (b2.y - b0.y) * dinv,
                                 (b2.z - b0.z) * dinv, (b2.w - b0.w) * dinv);
        float4 gdC = make_float4((c2.x - c0.x) * dinv, (c2.y - c0.y) * dinv,
                                 (c2.z - c0.z) * dinv, (c2.w - c0.w) * dinv);

        acc += relu_negdet(gdA.x, ghA.x, gwA.x, gdB.x, ghB.x, gwB.x, gdC.x, ghC.x, gwC.x)
             + relu_negdet(gdA.y, ghA.y, gwA.y, gdB.y, ghB.y, gwB.y, gdC.y, ghC.y, gwC.y)
             + relu_negdet(gdA.z, ghA.z, gwA.z, gdB.z, ghB.z, gwB.z, gdC.z, ghC.z, gwC.z)
             + relu_negdet(gdA.w, ghA.w, gwA.w, gdB.w, ghB.w, gwB.w, gdC.w, ghC.w, gwC.w);

        // slide the window
        a0 = a1; a1 = a2;
        b0 = b1; b1 = b2;
        c0 = c1; c1 = c2;
    }

    // deterministic block reduction: wave64 shuffle tree, then 5-word LDS
    #pragma unroll
    for (int off = 32; off > 0; off >>= 1)
        acc += __shfl_down(acc, off, 64);
    __shared__ float sred[TPB / 64];
    const int lane = tid & 63;
    const int wid  = tid >> 6;
    if (lane == 0) sred[wid] = acc;
    __syncthreads();
    if (tid == 0)
        part[blockIdx.x] = ((sred[0] + sred[1]) + (sred[2] + sred[3])) + sred[4];
}

// 768 partials -> mean. 3 independent loads per thread, f64 fixed-tree reduce
// (deterministic; f64 kills the ~2e8-magnitude sum's rounding concern).
__global__ __launch_bounds__(BLK2) void jac_final(const float* __restrict__ part,
                                                  float* __restrict__ out)
{
    const int t = threadIdx.x;
    double a = (double)part[t] + (double)part[t + 256] + (double)part[t + 512];
    __shared__ double s[BLK2];
    s[t] = a;
    __syncthreads();
    #pragma unroll
    for (int off = BLK2 / 2; off > 0; off >>= 1) {
        if (t < off) s[t] += s[t + off];
        __syncthreads();
    }
    if (t == 0)
        out[0] = (float)(s[0] / NVOX_D);
}

extern "C" void kernel_launch(void* const* d_in, const int* in_sizes, int n_in,
                              void* d_out, int out_size, void* d_ws, size_t ws_size,
                              hipStream_t stream)
{
    const float* u = (const float*)d_in[0];
    float* part = (float*)d_ws;              // 768 floats = 3 KB of scratch

    jac_partial<<<GRID1, TPB, 0, stream>>>(u, part);
    jac_final<<<1, BLK2, 0, stream>>>(part, (float*)d_out);
}

// Round 6
// 38.024 us; speedup vs baseline: 1.8046x; 1.0163x over previous
//
#include <hip/hip_runtime.h>

// Problem geometry (fixed by the reference): u is (B=2, C=3, D=160, H=192, W=160) float32.
#define Dd 160
#define Hh 192
#define Ww 160
#define HW (Hh * Ww)                       // 30720
#define DHW ((size_t)Dd * HW)              // 4,915,200
#define NVOX_D 9830400.0                   // 2 * 160*192*160

#define TH 8                                // h-rows per block
#define TD 10                               // d-planes per block (sliding window)
#define QROW (Ww / 4)                       // 40 float4-quads per row
#define TPB (QROW * TH)                     // 320 threads = 5 waves
#define NHT (Hh / TH)                       // 24
#define NDS (Dd / TD)                       // 16
#define GRID1 (2 * NHT * NDS)               // 768 blocks = exactly 3 per CU, 8*96
#define NXCD 8
#define CHUNK (GRID1 / NXCD)                // 96 logical blocks per XCD
#define BLK2 256

__device__ __forceinline__ float4 ld4(const float* p) {
    return *reinterpret_cast<const float4*>(p);
}

// w-gradient for a quad given its left/right edge scalars (jnp.gradient semantics)
__device__ __forceinline__ float4 wgrad(float4 cc, float lft, float rgt, int w0) {
    float4 g;
    g.x = (w0 == 0)      ? (cc.y - cc.x) : 0.5f * (cc.y - lft);
    g.y = 0.5f * (cc.z - cc.x);
    g.z = 0.5f * (cc.w - cc.y);
    g.w = (w0 + 4 == Ww) ? (cc.w - cc.z) : 0.5f * (rgt - cc.z);
    return g;
}

// relu(-det(J)) for one voxel given the 9 raw (unscaled) finite-difference grads.
__device__ __forceinline__ float relu_negdet(
    float gd0, float gh0, float gw0,
    float gd1, float gh1, float gw1,
    float gd2, float gh2, float gw2)
{
    const float sx = 79.5f;   // (D-1)/2 -> channel 0
    const float sy = 95.5f;   // (H-1)/2 -> channel 1
    const float sz = 79.5f;   // (W-1)/2 -> channel 2
    float dxx = fmaf(sx, gd0, 1.0f);
    float dxy = sx * gh0;
    float dxz = sx * gw0;
    float dyx = sy * gd1;
    float dyy = fmaf(sy, gh1, 1.0f);
    float dyz = sy * gw1;
    float dzx = sz * gd2;
    float dzy = sz * gh2;
    float dzz = fmaf(sz, gw2, 1.0f);
    float det = dxx * (dyy * dzz - dyz * dzy)
              + dxy * (dyz * dzx - dyx * dzz)
              + dxz * (dyx * dzy - dyy * dzx);
    return fmaxf(-det, 0.0f);
}

// Register-sliding d-march with:
//  - XCD-chunked bijective blockIdx swizzle (768 = 8*96): h/d-neighbor blocks
//    land on the SAME XCD's L2, so halo rows are L2 hits not HBM re-fetches.
//  - boustrophedon d-march (even ds ascend, odd ds descend): the plane shared
//    by ds and ds+1 is read by both at the SAME phase of their lifetime
//    (start/start or end/end) -> temporally adjacent -> L2-absorbed.
__global__ __launch_bounds__(TPB) void jac_partial(const float* __restrict__ u,
                                                   float* __restrict__ part)
{
    // bijective XCD swizzle: hardware round-robins blockIdx.x % 8 across XCDs;
    // give each XCD a contiguous run of 96 logical ids (ds fastest, then ht, b).
    const int lg  = (blockIdx.x % NXCD) * CHUNK + blockIdx.x / NXCD;
    const int ds  = lg % NDS;
    const int ht  = (lg / NDS) % NHT;
    const int b   = lg / (NDS * NHT);

    const int tid = threadIdx.x;
    const int wq  = tid % QROW;
    const int hh  = tid / QROW;
    const int h   = ht * TH + hh;
    const int w0  = wq * 4;

    // jnp.gradient edge handling via clamped indices (one-sided at h=0/H-1)
    const int hm = (h > 0)      ? h - 1 : 0;
    const int hp = (h < Hh - 1) ? h + 1 : Hh - 1;
    const float hinv = 1.0f / (float)(hp - hm);
    const int offm = (hm - h) * Ww;   // 0 or -Ww
    const int offp = (hp - h) * Ww;   // 0 or +Ww

    const int d0     = ds * TD;
    const int dir    = (ds & 1) ? -1 : 1;              // boustrophedon
    const int dstart = (dir > 0) ? d0 : d0 + TD - 1;

    // channel base pointers at (b, c, d=0, h, w0)
    const float* pcA = u + (size_t)(b * 3 + 0) * DHW + (size_t)h * Ww + w0;
    const float* pcB = pcA + DHW;
    const float* pcC = pcA + 2 * DHW;

    // sliding window: x0 = plane (dstart - dir) [behind], x1 = plane dstart
    float4 a0, a1, b0, b1, c0, c1;
    {
        int db = dstart - dir;
        db = (db < 0) ? 0 : ((db > Dd - 1) ? Dd - 1 : db);
        const size_t om = (size_t)db * HW;
        const size_t oc = (size_t)dstart * HW;
        a0 = ld4(pcA + om);  a1 = ld4(pcA + oc);
        b0 = ld4(pcB + om);  b1 = ld4(pcB + oc);
        c0 = ld4(pcC + om);  c1 = ld4(pcC + oc);
    }

    float acc = 0.0f;

    #pragma unroll 2
    for (int i = 0; i < TD; ++i) {
        const int d  = dstart + dir * i;
        int dn = d + dir;                               // incoming plane
        dn = (dn < 0) ? 0 : ((dn > Dd - 1) ? Dd - 1 : dn);
        // grad_d = (plane[d+1]-plane[d-1])*dinv; with march direction folded in:
        // ascending: x2=d+1,x0=d-1 -> (x2-x0)*dinv ; descending: x2=d-1,x0=d+1
        // -> (x2-x0)*(-dinv). Edge d=0/159: one-sided, divisor 1.
        const float dinvs = (float)dir * ((d > 0 && d < Dd - 1) ? 0.5f : 1.0f);
        const size_t od  = (size_t)d  * HW;
        const size_t odn = (size_t)dn * HW;

        // issue incoming-plane center loads first (consumed last -> latency hidden)
        float4 a2 = ld4(pcA + odn);
        float4 b2 = ld4(pcB + odn);
        float4 c2 = ld4(pcC + odn);

        const float* pdA = pcA + od;
        const float* pdB = pcB + od;
        const float* pdC = pcC + od;

        // h-neighbor quads at plane d (L1/L2 hits: siblings loaded them as centers)
        float4 rAm = ld4(pdA + offm), rAp = ld4(pdA + offp);
        float4 rBm = ld4(pdB + offm), rBp = ld4(pdB + offp);
        float4 rCm = ld4(pdC + offm), rCp = ld4(pdC + offp);

        // w-edge scalars (cache hits)
        float lA = (w0 > 0) ? pdA[-1] : 0.0f;
        float lB = (w0 > 0) ? pdB[-1] : 0.0f;
        float lC = (w0 > 0) ? pdC[-1] : 0.0f;
        float rA = (w0 + 4 < Ww) ? pdA[4] : 0.0f;
        float rB = (w0 + 4 < Ww) ? pdB[4] : 0.0f;
        float rC = (w0 + 4 < Ww) ? pdC[4] : 0.0f;

        // gradients (raw, unscaled)
        float4 gwA = wgrad(a1, lA, rA, w0);
        float4 gwB = wgrad(b1, lB, rB, w0);
        float4 gwC = wgrad(c1, lC, rC, w0);

        float4 ghA = make_float4((rAp.x - rAm.x) * hinv, (rAp.y - rAm.y) * hinv,
                                 (rAp.z - rAm.z) * hinv, (rAp.w - rAm.w) * hinv);
        float4 ghB = make_float4((rBp.x - rBm.x) * hinv, (rBp.y - rBm.y) * hinv,
                                 (rBp.z - rBm.z) * hinv, (rBp.w - rBm.w) * hinv);
        float4 ghC = make_float4((rCp.x - rCm.x) * hinv, (rCp.y - rCm.y) * hinv,
                                 (rCp.z - rCm.z) * hinv, (rCp.w - rCm.w) * hinv);

        float4 gdA = make_float4((a2.x - a0.x) * dinvs, (a2.y - a0.y) * dinvs,
                                 (a2.z - a0.z) * dinvs, (a2.w - a0.w) * dinvs);
        float4 gdB = make_float4((b2.x - b0.x) * dinvs, (b2.y - b0.y) * dinvs,
                                 (b2.z - b0.z) * dinvs, (b2.w - b0.w) * dinvs);
        float4 gdC = make_float4((c2.x - c0.x) * dinvs, (c2.y - c0.y) * dinvs,
                                 (c2.z - c0.z) * dinvs, (c2.w - c0.w) * dinvs);

        acc += relu_negdet(gdA.x, ghA.x, gwA.x, gdB.x, ghB.x, gwB.x, gdC.x, ghC.x, gwC.x)
             + relu_negdet(gdA.y, ghA.y, gwA.y, gdB.y, ghB.y, gwB.y, gdC.y, ghC.y, gwC.y)
             + relu_negdet(gdA.z, ghA.z, gwA.z, gdB.z, ghB.z, gwB.z, gdC.z, ghC.z, gwC.z)
             + relu_negdet(gdA.w, ghA.w, gwA.w, gdB.w, ghB.w, gwB.w, gdC.w, ghC.w, gwC.w);

        // slide the window
        a0 = a1; a1 = a2;
        b0 = b1; b1 = b2;
        c0 = c1; c1 = c2;
    }

    // deterministic block reduction: wave64 shuffle tree, then 5-word LDS
    #pragma unroll
    for (int off = 32; off > 0; off >>= 1)
        acc += __shfl_down(acc, off, 64);
    __shared__ float sred[TPB / 64];
    const int lane = tid & 63;
    const int wid  = tid >> 6;
    if (lane == 0) sred[wid] = acc;
    __syncthreads();
    if (tid == 0)
        part[lg] = ((sred[0] + sred[1]) + (sred[2] + sred[3])) + sred[4];
}

// 768 partials -> mean. 3 independent loads per thread, f64 fixed-tree reduce
// (deterministic; f64 kills the ~2e8-magnitude sum's rounding concern).
__global__ __launch_bounds__(BLK2) void jac_final(const float* __restrict__ part,
                                                  float* __restrict__ out)
{
    const int t = threadIdx.x;
    double a = (double)part[t] + (double)part[t + 256] + (double)part[t + 512];
    __shared__ double s[BLK2];
    s[t] = a;
    __syncthreads();
    #pragma unroll
    for (int off = BLK2 / 2; off > 0; off >>= 1) {
        if (t < off) s[t] += s[t + off];
        __syncthreads();
    }
    if (t == 0)
        out[0] = (float)(s[0] / NVOX_D);
}

extern "C" void kernel_launch(void* const* d_in, const int* in_sizes, int n_in,
                              void* d_out, int out_size, void* d_ws, size_t ws_size,
                              hipStream_t stream)
{
    const float* u = (const float*)d_in[0];
    float* part = (float*)d_ws;              // 768 floats = 3 KB of scratch

    jac_partial<<<GRID1, TPB, 0, stream>>>(u, part);
    jac_final<<<1, BLK2, 0, stream>>>(part, (float*)d_out);
}